// Round 1
// baseline (605.576 us; speedup 1.0000x reference)
//
#include <hip/hip_runtime.h>

// SVConvTranspose2d: out[n,o,oh,ow] = bias[o] +
//   sum_{kh,kw,i} x[n,i,oh+2-kh,ow+2-kw] * weight[i,o,kh,kw,oh+2-kh,ow+2-kw]
// Pure gather: each weight element is read exactly once across the grid.

constexpr int Nn   = 4;
constexpr int CIN  = 16;
constexpr int COUT = 16;
constexpr int KHs  = 5;
constexpr int KWs  = 5;
constexpr int Hs   = 128;
constexpr int Ws   = 128;
constexpr int HW   = Hs * Ws;                       // 16384
constexpr int W_I_STRIDE = COUT * KHs * KWs * HW;   // 6,553,600 floats between i-slices

__global__ __launch_bounds__(256, 4) void svconvt_gather(
    const float* __restrict__ x, const float* __restrict__ wgt,
    const float* __restrict__ bias, float* __restrict__ out)
{
    const int tid = threadIdx.x;
    const int ow  = tid & (Ws - 1);          // lane -> ow (contiguous w => coalesced)
    const int oh  = (blockIdx.x << 1) | (tid >> 7);   // 2 output rows per block
    const int o   = blockIdx.y;

    float acc[Nn] = {0.f, 0.f, 0.f, 0.f};

    #pragma unroll 1
    for (int kh = 0; kh < KHs; ++kh) {
        const int h = oh + 2 - kh;
        if ((unsigned)h >= (unsigned)Hs) continue;    // wave-uniform branch
        #pragma unroll
        for (int kw = 0; kw < KWs; ++kw) {
            const int wc = ow + 2 - kw;
            if ((unsigned)wc >= (unsigned)Ws) continue;   // diverges only at border lanes
            const int sp = h * Ws + wc;
            const float* wp = wgt + ((o * KHs + kh) * KWs + kw) * HW + sp;
            const float* xp = x + sp;
            #pragma unroll
            for (int i = 0; i < CIN; ++i) {
                const float wv = wp[i * W_I_STRIDE];      // read-once weight stream
                #pragma unroll
                for (int n = 0; n < Nn; ++n)
                    acc[n] = fmaf(xp[(n * CIN + i) * HW], wv, acc[n]);  // x is L1/L2-hot
            }
        }
    }

    const float b = bias[o];
    #pragma unroll
    for (int n = 0; n < Nn; ++n)
        out[((n * COUT + o) * Hs + oh) * Ws + ow] = acc[n] + b;
}

extern "C" void kernel_launch(void* const* d_in, const int* in_sizes, int n_in,
                              void* d_out, int out_size, void* d_ws, size_t ws_size,
                              hipStream_t stream) {
    const float* x    = (const float*)d_in[0];   // (4,16,128,128)
    const float* wgt  = (const float*)d_in[1];   // (16,16,5,5,128,128)
    const float* bias = (const float*)d_in[2];   // (1,16,1,1)
    float* out        = (float*)d_out;           // (4,16,128,128)

    dim3 grid(Hs / 2, COUT);
    svconvt_gather<<<grid, dim3(256), 0, stream>>>(x, wgt, bias, out);
}